// Round 1
// baseline (1222.562 us; speedup 1.0000x reference)
//
#include <hip/hip_runtime.h>
#include <math.h>

#define B_ 512
#define N_ 32
#define D_ 300
#define R_ 6
#define E_ 256
#define NG_ 50000
#define NS_ 25000

#define KTOT (7*D_)          // 2100: 6 relation rows + W0 row
#define YSZ  (B_*KTOT)       // floats
#define XSZ  (B_*D_)         // floats

// ---------------- K1a: collapse graph to Y[b, 7, 300] ----------------
__global__ __launch_bounds__(256) void k1a_coef_y(
    const float* __restrict__ x, const int* __restrict__ ei,
    const int* __restrict__ et, float* __restrict__ Y)
{
  int b = blockIdx.x;
  int tid = threadIdx.x;
  __shared__ int srcs[E_], dsts[E_], ets[E_];
  __shared__ int degc[R_*N_];
  __shared__ float coef[R_*N_];

  srcs[tid] = ei[b*2*E_ + tid];
  dsts[tid] = ei[b*2*E_ + E_ + tid];
  ets[tid]  = et[b*E_ + tid];
  if (tid < R_*N_) { degc[tid] = 0; coef[tid] = 0.0f; }
  __syncthreads();

  atomicAdd(&degc[ets[tid]*N_ + dsts[tid]], 1);
  __syncthreads();

  if (dsts[tid] == 0) {
    int r = ets[tid];
    float ds = 1.0f + (float)degc[r*N_ + srcs[tid]];
    float dd = 1.0f + (float)degc[r*N_ + 0];
    atomicAdd(&coef[r*N_ + srcs[tid]], rsqrtf(ds*dd));
  }
  if (tid < R_) {
    atomicAdd(&coef[tid*N_ + 0], 1.0f/(1.0f + (float)degc[tid*N_]));
  }
  __syncthreads();

  const float* xb = x + (size_t)b*N_*D_;
  float* Yb = Y + (size_t)b*KTOT;
  for (int k = tid; k < D_; k += 256) {
    #pragma unroll
    for (int r = 0; r < R_; ++r) {
      float acc = 0.0f;
      for (int n = 0; n < N_; ++n) {
        float c = coef[r*N_ + n];          // uniform across threads -> uniform branch
        if (c != 0.0f) acc += c * xb[n*D_ + k];
      }
      Yb[r*D_ + k] = acc;
    }
    Yb[6*D_ + k] = xb[k];                  // x[b,0,:] for the W0 term
  }
}

// ---------------- K1b: x0h = leaky(Y @ [W_rel;W0]) ----------------
#define BM1 4
__global__ __launch_bounds__(320) void k1b_h0(
    const float* __restrict__ Y, const float* __restrict__ Wrel,
    const float* __restrict__ W0, float* __restrict__ X0H)
{
  int m0 = blockIdx.x * BM1;
  int c = threadIdx.x;
  if (c >= D_) return;
  float acc[BM1];
  #pragma unroll
  for (int m = 0; m < BM1; ++m) acc[m] = 0.0f;

  for (int k0 = 0; k0 < KTOT; k0 += 4) {
    const float* Wp = (k0 < 6*D_) ? (Wrel + (size_t)k0*D_) : (W0 + (size_t)(k0 - 6*D_)*D_);
    float w0 = Wp[0*D_ + c];
    float w1 = Wp[1*D_ + c];
    float w2 = Wp[2*D_ + c];
    float w3 = Wp[3*D_ + c];
    #pragma unroll
    for (int m = 0; m < BM1; ++m) {
      const float4 xv = *reinterpret_cast<const float4*>(&Y[(size_t)(m0+m)*KTOT + k0]);
      acc[m] = fmaf(xv.x, w0, fmaf(xv.y, w1, fmaf(xv.z, w2, fmaf(xv.w, w3, acc[m]))));
    }
  }
  #pragma unroll
  for (int m = 0; m < BM1; ++m) {
    float h = acc[m];
    h = (h >= 0.0f) ? h : 0.1f*h;
    X0H[(size_t)(m0+m)*D_ + c] = h;
  }
}

// ---------------- K2: logits = x0h @ W + b  -> d_out ----------------
#define GCB 196   // ceil(50000/256)
#define SCB 98    // ceil(25000/256)
__global__ __launch_bounds__(256) void k2_logits(
    const float* __restrict__ X0H,
    const float* __restrict__ Wg, const float* __restrict__ bg,
    const float* __restrict__ Ws, const float* __restrict__ bs,
    float* __restrict__ out)
{
  int cb = blockIdx.x;
  int m0 = blockIdx.y * 64;
  const float* W; const float* bias; float* o; int C;
  if (cb < GCB) { W = Wg; bias = bg; o = out;                     C = NG_; }
  else          { W = Ws; bias = bs; o = out + (size_t)B_*NG_;    C = NS_; cb -= GCB; }
  int c = cb*256 + threadIdx.x;
  bool ok = (c < C);
  int cc = ok ? c : 0;

  float acc[64];
  #pragma unroll
  for (int m = 0; m < 64; ++m) acc[m] = 0.0f;

  for (int k0 = 0; k0 < D_; k0 += 4) {
    float w0 = W[(size_t)(k0+0)*C + cc];
    float w1 = W[(size_t)(k0+1)*C + cc];
    float w2 = W[(size_t)(k0+2)*C + cc];
    float w3 = W[(size_t)(k0+3)*C + cc];
    #pragma unroll
    for (int m = 0; m < 64; ++m) {
      // uniform address across the wave -> scalar-load friendly
      const float4 xv = *reinterpret_cast<const float4*>(&X0H[(size_t)(m0+m)*D_ + k0]);
      acc[m] = fmaf(xv.x, w0, fmaf(xv.y, w1, fmaf(xv.z, w2, fmaf(xv.w, w3, acc[m]))));
    }
  }
  if (ok) {
    float bv = bias[c];
    #pragma unroll
    for (int m = 0; m < 64; ++m) {
      o[(size_t)(m0+m)*C + c] = acc[m] + bv;
    }
  }
}

// ---------------- K3: per-row logsumexp -> lse[1024] ----------------
__global__ __launch_bounds__(256) void k3_lse(
    const float* __restrict__ out, float* __restrict__ lse)
{
  int row = blockIdx.x;
  const float* p; int C;
  if (row < B_) { p = out + (size_t)row*NG_; C = NG_; }
  else          { p = out + (size_t)B_*NG_ + (size_t)(row - B_)*NS_; C = NS_; }

  float m = -1e30f, s = 0.0f;
  for (int i = threadIdx.x; i < C; i += 256) {
    float v = p[i];
    float mn = fmaxf(m, v);
    s = s*__expf(m - mn) + __expf(v - mn);
    m = mn;
  }
  #pragma unroll
  for (int off = 32; off > 0; off >>= 1) {
    float m2 = __shfl_xor(m, off);
    float s2 = __shfl_xor(s, off);
    float mn = fmaxf(m, m2);
    s = s*__expf(m - mn) + s2*__expf(m2 - mn);
    m = mn;
  }
  __shared__ float ms[4], ss[4];
  int wid = threadIdx.x >> 6;
  if ((threadIdx.x & 63) == 0) { ms[wid] = m; ss[wid] = s; }
  __syncthreads();
  if (threadIdx.x == 0) {
    float M = ms[0], S = ss[0];
    #pragma unroll
    for (int w = 1; w < 4; ++w) {
      float mn = fmaxf(M, ms[w]);
      S = S*__expf(M - mn) + ss[w]*__expf(ms[w] - mn);
      M = mn;
    }
    lse[row] = M + __logf(S);
  }
}

// ---------------- K4: out -= lse[row], float4 ----------------
__global__ void k4_sub(float* __restrict__ out, const float* __restrict__ lse)
{
  const size_t g4 = (size_t)B_*NG_/4;                 // 6,400,000
  const size_t total4 = g4 + (size_t)B_*NS_/4;        // 9,600,000
  size_t stride = (size_t)gridDim.x * blockDim.x;
  for (size_t i4 = (size_t)blockIdx.x*blockDim.x + threadIdx.x; i4 < total4; i4 += stride) {
    int row;
    if (i4 < g4) row = (int)(i4 / (NG_/4));
    else         row = B_ + (int)((i4 - g4) / (NS_/4));
    float l = lse[row];
    float4 v = reinterpret_cast<float4*>(out)[i4];
    v.x -= l; v.y -= l; v.z -= l; v.w -= l;
    reinterpret_cast<float4*>(out)[i4] = v;
  }
}

extern "C" void kernel_launch(void* const* d_in, const int* in_sizes, int n_in,
                              void* d_out, int out_size, void* d_ws, size_t ws_size,
                              hipStream_t stream)
{
  const float* x    = (const float*)d_in[0];
  const int*   ei   = (const int*)  d_in[1];
  const int*   et   = (const int*)  d_in[2];
  const float* Wrel = (const float*)d_in[3];
  const float* W0   = (const float*)d_in[4];
  const float* Wg   = (const float*)d_in[5];
  const float* bg   = (const float*)d_in[6];
  const float* Ws   = (const float*)d_in[7];
  const float* bs   = (const float*)d_in[8];
  float* out = (float*)d_out;

  float* wsf  = (float*)d_ws;
  float* Y    = wsf;                 // [512][2100]
  float* X0H  = wsf + YSZ;           // [512][300]
  float* LSE  = wsf + YSZ + XSZ;     // [1024]

  k1a_coef_y<<<B_, 256, 0, stream>>>(x, ei, et, Y);
  k1b_h0<<<B_/BM1, 320, 0, stream>>>(Y, Wrel, W0, X0H);
  k2_logits<<<dim3(GCB + SCB, B_/64), 256, 0, stream>>>(X0H, Wg, bg, Ws, bs, out);
  k3_lse<<<2*B_, 256, 0, stream>>>(out, LSE);
  k4_sub<<<2048, 256, 0, stream>>>(out, LSE);
}

// Round 2
// 893.942 us; speedup vs baseline: 1.3676x; 1.3676x over previous
//
#include <hip/hip_runtime.h>
#include <hip/hip_bf16.h>
#include <math.h>

#define B_ 512
#define N_ 32
#define D_ 300
#define R_ 6
#define E_ 256
#define NG_ 50000
#define NS_ 25000

#define KTOT (7*D_)          // 2100: 6 relation rows + W0 row
#define YSZ  (B_*KTOT)       // floats
#define XSZ  (B_*D_)         // floats

typedef __attribute__((ext_vector_type(8))) short short8;
typedef __attribute__((ext_vector_type(4))) float f32x4;

__device__ __forceinline__ unsigned short f2bf(float f) {
  __hip_bfloat16 h = __float2bfloat16(f);
  return *reinterpret_cast<unsigned short*>(&h);
}

// ---------------- K1a: collapse graph to Y[b, 7, 300] ----------------
__global__ __launch_bounds__(256) void k1a_coef_y(
    const float* __restrict__ x, const int* __restrict__ ei,
    const int* __restrict__ et, float* __restrict__ Y)
{
  int b = blockIdx.x;
  int tid = threadIdx.x;
  __shared__ int srcs[E_], dsts[E_], ets[E_];
  __shared__ int degc[R_*N_];
  __shared__ float coef[R_*N_];

  srcs[tid] = ei[b*2*E_ + tid];
  dsts[tid] = ei[b*2*E_ + E_ + tid];
  ets[tid]  = et[b*E_ + tid];
  if (tid < R_*N_) { degc[tid] = 0; coef[tid] = 0.0f; }
  __syncthreads();

  atomicAdd(&degc[ets[tid]*N_ + dsts[tid]], 1);
  __syncthreads();

  if (dsts[tid] == 0) {
    int r = ets[tid];
    float ds = 1.0f + (float)degc[r*N_ + srcs[tid]];
    float dd = 1.0f + (float)degc[r*N_ + 0];
    atomicAdd(&coef[r*N_ + srcs[tid]], rsqrtf(ds*dd));
  }
  if (tid < R_) {
    atomicAdd(&coef[tid*N_ + 0], 1.0f/(1.0f + (float)degc[tid*N_]));
  }
  __syncthreads();

  const float* xb = x + (size_t)b*N_*D_;
  float* Yb = Y + (size_t)b*KTOT;
  for (int k = tid; k < D_; k += 256) {
    #pragma unroll
    for (int r = 0; r < R_; ++r) {
      float acc = 0.0f;
      for (int n = 0; n < N_; ++n) {
        float c = coef[r*N_ + n];          // uniform across threads
        if (c != 0.0f) acc += c * xb[n*D_ + k];
      }
      Yb[r*D_ + k] = acc;
    }
    Yb[6*D_ + k] = xb[k];                  // x[b,0,:] for the W0 term
  }
}

// ---------------- MFMA GEMM: out[M x C] = A[M x K] @ B[K x C] (+bias / leaky) ----------------
// BM=BN=128, BK=64, 256 threads = 4 waves in 2x2, each wave 64x64 via 4x4 frags of 16x16x32.
__global__ __launch_bounds__(256) void gemm_mfma(
    const float* __restrict__ A, int lda, int K, int Ksplit,
    const float* __restrict__ B0f, const float* __restrict__ B1f,
    int ldb, int C,
    const float* __restrict__ bias, int leaky,
    float* __restrict__ out, int ldo)
{
  __shared__ unsigned short As[128*72];   // [row][k]  stride 72
  __shared__ unsigned short Bs[128*72];   // [col][k]  stride 72 (transposed)

  const int m0 = blockIdx.x * 128;
  const int c0 = blockIdx.y * 128;
  const int tid = threadIdx.x;
  const int lane = tid & 63, wid = tid >> 6;
  const int wm = wid >> 1, wn = wid & 1;
  const int lr = lane & 15, lg = lane >> 4;

  f32x4 acc[4][4];
  #pragma unroll
  for (int a = 0; a < 4; ++a)
    #pragma unroll
    for (int b = 0; b < 4; ++b) acc[a][b] = (f32x4){0.f, 0.f, 0.f, 0.f};

  // staging thread mapping
  const int ar  = tid >> 4;        // A: base row 0..15
  const int ac4 = tid & 15;        // A: float4 index along k
  const int bcol = tid & 127;      // B: one column per thread
  const int brb  = (tid >> 7) * 4; // B: k sub-block base 0 or 4
  const int gc = c0 + bcol;
  const bool cok = (gc < C);

  const int nkt = (K + 63) / 64;
  for (int t = 0; t < nkt; ++t) {
    const int kt = t * 64;
    __syncthreads();
    // ---- stage A tile: rows m0..m0+127, k kt..kt+63 (fp32 -> bf16) ----
    #pragma unroll
    for (int rr = 0; rr < 128; rr += 16) {
      int row = rr + ar;
      float4 v = make_float4(0.f, 0.f, 0.f, 0.f);
      int k = kt + ac4 * 4;
      if (k < K) v = *reinterpret_cast<const float4*>(&A[(size_t)(m0 + row) * lda + k]);
      ushort4 u;
      u.x = f2bf(v.x); u.y = f2bf(v.y); u.z = f2bf(v.z); u.w = f2bf(v.w);
      *reinterpret_cast<ushort4*>(&As[row * 72 + ac4 * 4]) = u;
    }
    // ---- stage B tile transposed: cols c0..c0+127, k kt..kt+63 ----
    #pragma unroll
    for (int ii = 0; ii < 8; ++ii) {
      int r0 = brb + ii * 8;
      float v0 = 0.f, v1 = 0.f, v2 = 0.f, v3 = 0.f;
      if (cok) {
        #pragma unroll
        for (int j = 0; j < 4; ++j) {
          int k = kt + r0 + j;
          float xv = 0.f;
          if (k < K) {
            const float* brow = (k < Ksplit) ? (B0f + (size_t)k * ldb)
                                             : (B1f + (size_t)(k - Ksplit) * ldb);
            xv = brow[gc];
          }
          if (j == 0) v0 = xv; else if (j == 1) v1 = xv; else if (j == 2) v2 = xv; else v3 = xv;
        }
      }
      ushort4 u;
      u.x = f2bf(v0); u.y = f2bf(v1); u.z = f2bf(v2); u.w = f2bf(v3);
      *reinterpret_cast<ushort4*>(&Bs[bcol * 72 + r0]) = u;
    }
    __syncthreads();
    // ---- MFMA over the 64-k tile ----
    const unsigned short* Ab = &As[(wm * 64 + lr) * 72 + lg * 8];
    const unsigned short* Bb = &Bs[(wn * 64 + lr) * 72 + lg * 8];
    #pragma unroll
    for (int kk = 0; kk < 2; ++kk) {
      short8 af[4], bf[4];
      #pragma unroll
      for (int a = 0; a < 4; ++a)
        af[a] = *reinterpret_cast<const short8*>(Ab + a * 16 * 72 + kk * 32);
      #pragma unroll
      for (int b = 0; b < 4; ++b)
        bf[b] = *reinterpret_cast<const short8*>(Bb + b * 16 * 72 + kk * 32);
      #pragma unroll
      for (int a = 0; a < 4; ++a)
        #pragma unroll
        for (int b = 0; b < 4; ++b)
          acc[a][b] = __builtin_amdgcn_mfma_f32_16x16x32_bf16(af[a], bf[b], acc[a][b], 0, 0, 0);
    }
  }

  // ---- epilogue: bias / leaky, fp32 store ----
  #pragma unroll
  for (int a = 0; a < 4; ++a) {
    int row = m0 + wm * 64 + a * 16 + lg * 4;
    #pragma unroll
    for (int b = 0; b < 4; ++b) {
      int col = c0 + wn * 64 + b * 16 + lr;
      if (col < C) {
        float bv = bias ? bias[col] : 0.f;
        #pragma unroll
        for (int i = 0; i < 4; ++i) {
          float val = acc[a][b][i] + bv;
          if (leaky) val = (val >= 0.f) ? val : 0.1f * val;
          out[(size_t)(row + i) * ldo + col] = val;
        }
      }
    }
  }
}

// ---------------- K3: per-row logsumexp -> lse[1024] ----------------
__global__ __launch_bounds__(256) void k3_lse(
    const float* __restrict__ out, float* __restrict__ lse)
{
  int row = blockIdx.x;
  const float* p; int C;
  if (row < B_) { p = out + (size_t)row*NG_; C = NG_; }
  else          { p = out + (size_t)B_*NG_ + (size_t)(row - B_)*NS_; C = NS_; }

  float m = -1e30f, s = 0.0f;
  for (int i = threadIdx.x; i < C; i += 256) {
    float v = p[i];
    float mn = fmaxf(m, v);
    s = s*__expf(m - mn) + __expf(v - mn);
    m = mn;
  }
  #pragma unroll
  for (int off = 32; off > 0; off >>= 1) {
    float m2 = __shfl_xor(m, off);
    float s2 = __shfl_xor(s, off);
    float mn = fmaxf(m, m2);
    s = s*__expf(m - mn) + s2*__expf(m2 - mn);
    m = mn;
  }
  __shared__ float ms[4], ss[4];
  int wid = threadIdx.x >> 6;
  if ((threadIdx.x & 63) == 0) { ms[wid] = m; ss[wid] = s; }
  __syncthreads();
  if (threadIdx.x == 0) {
    float M = ms[0], S = ss[0];
    #pragma unroll
    for (int w = 1; w < 4; ++w) {
      float mn = fmaxf(M, ms[w]);
      S = S*__expf(M - mn) + ss[w]*__expf(ms[w] - mn);
      M = mn;
    }
    lse[row] = M + __logf(S);
  }
}

// ---------------- K4: out -= lse[row], float4 ----------------
__global__ void k4_sub(float* __restrict__ out, const float* __restrict__ lse)
{
  const size_t g4 = (size_t)B_*NG_/4;
  const size_t total4 = g4 + (size_t)B_*NS_/4;
  size_t stride = (size_t)gridDim.x * blockDim.x;
  for (size_t i4 = (size_t)blockIdx.x*blockDim.x + threadIdx.x; i4 < total4; i4 += stride) {
    int row;
    if (i4 < g4) row = (int)(i4 / (NG_/4));
    else         row = B_ + (int)((i4 - g4) / (NS_/4));
    float l = lse[row];
    float4 v = reinterpret_cast<float4*>(out)[i4];
    v.x -= l; v.y -= l; v.z -= l; v.w -= l;
    reinterpret_cast<float4*>(out)[i4] = v;
  }
}

extern "C" void kernel_launch(void* const* d_in, const int* in_sizes, int n_in,
                              void* d_out, int out_size, void* d_ws, size_t ws_size,
                              hipStream_t stream)
{
  const float* x    = (const float*)d_in[0];
  const int*   ei   = (const int*)  d_in[1];
  const int*   et   = (const int*)  d_in[2];
  const float* Wrel = (const float*)d_in[3];
  const float* W0   = (const float*)d_in[4];
  const float* Wg   = (const float*)d_in[5];
  const float* bg   = (const float*)d_in[6];
  const float* Ws   = (const float*)d_in[7];
  const float* bs   = (const float*)d_in[8];
  float* out = (float*)d_out;

  float* wsf  = (float*)d_ws;
  float* Y    = wsf;                 // [512][2100]
  float* X0H  = wsf + YSZ;           // [512][300]
  float* LSE  = wsf + YSZ + XSZ;     // [1024]

  k1a_coef_y<<<B_, 256, 0, stream>>>(x, ei, et, Y);

  // K1b: X0H = leaky(Y[512x2100] @ [Wrel;W0][2100x300])
  gemm_mfma<<<dim3(4, 3), 256, 0, stream>>>(
      Y, KTOT, KTOT, 6*D_, Wrel, W0, D_, D_, nullptr, 1, X0H, D_);

  // K2g: out[:, :NG] = X0H @ Wg + bg
  gemm_mfma<<<dim3(4, (NG_ + 127)/128), 256, 0, stream>>>(
      X0H, D_, D_, D_, Wg, Wg, NG_, NG_, bg, 0, out, NG_);

  // K2s: out[:, NG:] = X0H @ Ws + bs
  gemm_mfma<<<dim3(4, (NS_ + 127)/128), 256, 0, stream>>>(
      X0H, D_, D_, D_, Ws, Ws, NS_, NS_, bs, 0, out + (size_t)B_*NG_, NS_);

  k3_lse<<<2*B_, 256, 0, stream>>>(out, LSE);
  k4_sub<<<2048, 256, 0, stream>>>(out, LSE);
}

// Round 3
// 313.590 us; speedup vs baseline: 3.8986x; 2.8507x over previous
//
#include <hip/hip_runtime.h>
#include <hip/hip_bf16.h>
#include <math.h>

#define B_ 512
#define N_ 32
#define D_ 300
#define R_ 6
#define E_ 256
#define NG_ 50000
#define NS_ 25000

#define KTOT 2100      // 6*300 (Wrel) + 300 (W0)
#define YLD  2112      // Y leading dim (fp32, padded to 33*64)
#define XLD  320       // X0H bf16 leading dim (padded to 5*64)
#define PLD  304       // K1b partial leading dim (fp32)

typedef __attribute__((ext_vector_type(8))) short short8;
typedef __attribute__((ext_vector_type(4))) float f32x4;

__device__ __forceinline__ unsigned short f2bf(float f) {
  __hip_bfloat16 h = __float2bfloat16(f);
  return *reinterpret_cast<unsigned short*>(&h);
}

// ---------------- K1a: collapse graph to Y[b, 2112] (zero-padded) ----------------
__global__ __launch_bounds__(256) void k1a_coef_y(
    const float* __restrict__ x, const int* __restrict__ ei,
    const int* __restrict__ et, float* __restrict__ Y)
{
  int b = blockIdx.x;
  int tid = threadIdx.x;
  __shared__ int srcs[E_], dsts[E_], ets[E_];
  __shared__ int degc[R_*N_];
  __shared__ float coef[R_*N_];

  srcs[tid] = ei[b*2*E_ + tid];
  dsts[tid] = ei[b*2*E_ + E_ + tid];
  ets[tid]  = et[b*E_ + tid];
  if (tid < R_*N_) { degc[tid] = 0; coef[tid] = 0.0f; }
  __syncthreads();

  atomicAdd(&degc[ets[tid]*N_ + dsts[tid]], 1);
  __syncthreads();

  if (dsts[tid] == 0) {
    int r = ets[tid];
    float ds = 1.0f + (float)degc[r*N_ + srcs[tid]];
    float dd = 1.0f + (float)degc[r*N_ + 0];
    atomicAdd(&coef[r*N_ + srcs[tid]], rsqrtf(ds*dd));
  }
  if (tid < R_) {
    atomicAdd(&coef[tid*N_ + 0], 1.0f/(1.0f + (float)degc[tid*N_]));
  }
  __syncthreads();

  const float* xb = x + (size_t)b*N_*D_;
  float* Yb = Y + (size_t)b*YLD;
  for (int k = tid; k < D_; k += 256) {
    #pragma unroll
    for (int r = 0; r < R_; ++r) {
      float acc = 0.0f;
      for (int n = 0; n < N_; ++n) {
        float c = coef[r*N_ + n];          // uniform across threads
        if (c != 0.0f) acc += c * xb[n*D_ + k];
      }
      Yb[r*D_ + k] = acc;
    }
    Yb[6*D_ + k] = xb[k];                  // x[b,0,:] for the W0 term
  }
  if (tid < YLD - KTOT) Yb[KTOT + tid] = 0.0f;   // zero k-pad
}

// ---------------- MFMA GEMM: BM=256, BN=64, BK=64, 4 waves stacked on M ----------------
// out[z] += A[256 rows x K] @ B[K x 64 cols]  for this block's K-tile subset.
template<int ABF16>
__global__ __launch_bounds__(256) void gemm2(
    const void* __restrict__ Av, int lda, int K, int nkt, int Ksplit,
    const float* __restrict__ B0, const float* __restrict__ B1, int ldb, int C,
    const float* __restrict__ bias, float* __restrict__ out, int ldo, int zstride,
    int nmb, int ncb, int nz, int swz)
{
  __shared__ unsigned short As[256*72];   // [row][k] stride 72
  __shared__ unsigned short Bs[64*72];    // [col][k] stride 72 (transposed)

  int id = blockIdx.x;
  if (swz) {  // bijective XCD-chunked swizzle (m204 variant)
    int nwg = gridDim.x;
    int q = nwg >> 3, r = nwg & 7;
    int xcd = id & 7, loc = id >> 3;
    id = (xcd < r ? xcd*(q+1) : r*(q+1) + (xcd-r)*q) + loc;
  }
  const int plane = nmb * ncb;
  const int z  = id / plane;
  const int r2 = id % plane;
  const int mb = r2 % nmb;        // consecutive ids share the col-block -> same XCD L2
  const int cb = r2 / nmb;
  const int m0 = mb * 256;
  const int c0 = cb * 64;

  const int tid = threadIdx.x;
  const int lane = tid & 63, wid = tid >> 6;
  const int lr = lane & 15, lg = lane >> 4;

  f32x4 acc[4][4];
  #pragma unroll
  for (int a = 0; a < 4; ++a)
    #pragma unroll
    for (int b = 0; b < 4; ++b) acc[a][b] = (f32x4){0.f, 0.f, 0.f, 0.f};

  for (int t = z; t < nkt; t += nz) {
    const int kt = t * 64;
    __syncthreads();
    // ---- stage A tile (rows m0..m0+255, k kt..kt+63) ----
    if constexpr (ABF16) {
      const unsigned short* A = (const unsigned short*)Av;
      const int s = tid & 7, r0 = tid >> 3;
      #pragma unroll
      for (int p = 0; p < 8; ++p) {
        int row = r0 + p*32;
        short8 v = *reinterpret_cast<const short8*>(&A[(size_t)(m0+row)*lda + kt + s*8]);
        *reinterpret_cast<short8*>(&As[row*72 + s*8]) = v;
      }
    } else {
      const float* A = (const float*)Av;
      const int s = tid & 15, r0 = tid >> 4;
      #pragma unroll
      for (int p = 0; p < 16; ++p) {
        int row = r0 + p*16;
        float4 v = *reinterpret_cast<const float4*>(&A[(size_t)(m0+row)*lda + kt + s*4]);
        ushort4 u;
        u.x = f2bf(v.x); u.y = f2bf(v.y); u.z = f2bf(v.z); u.w = f2bf(v.w);
        *reinterpret_cast<ushort4*>(&As[row*72 + s*4]) = u;
      }
    }
    // ---- stage B tile transposed (k kt..kt+63, cols c0..c0+63) ----
    {
      const int c4 = tid & 15, kr = tid >> 4;
      #pragma unroll
      for (int p = 0; p < 4; ++p) {
        int k = kt + p*16 + kr;
        float4 v = make_float4(0.f, 0.f, 0.f, 0.f);
        if (k < K && c0 + c4*4 + 4 <= C) {
          const float* brow = (k < Ksplit) ? (B0 + (size_t)k*ldb)
                                           : (B1 + (size_t)(k-Ksplit)*ldb);
          v = *reinterpret_cast<const float4*>(&brow[c0 + c4*4]);
        }
        int kk = p*16 + kr;
        Bs[(c4*4+0)*72 + kk] = f2bf(v.x);
        Bs[(c4*4+1)*72 + kk] = f2bf(v.y);
        Bs[(c4*4+2)*72 + kk] = f2bf(v.z);
        Bs[(c4*4+3)*72 + kk] = f2bf(v.w);
      }
    }
    __syncthreads();
    // ---- MFMA over the 64-k tile: wave wid owns rows wid*64..wid*64+63 ----
    const unsigned short* Ab = &As[(wid*64 + lr)*72 + lg*8];
    const unsigned short* Bb = &Bs[lr*72 + lg*8];
    #pragma unroll
    for (int kk = 0; kk < 2; ++kk) {
      short8 af[4], bfr[4];
      #pragma unroll
      for (int a = 0; a < 4; ++a)
        af[a] = *reinterpret_cast<const short8*>(Ab + a*16*72 + kk*32);
      #pragma unroll
      for (int b = 0; b < 4; ++b)
        bfr[b] = *reinterpret_cast<const short8*>(Bb + b*16*72 + kk*32);
      #pragma unroll
      for (int a = 0; a < 4; ++a)
        #pragma unroll
        for (int b = 0; b < 4; ++b)
          acc[a][b] = __builtin_amdgcn_mfma_f32_16x16x32_bf16(af[a], bfr[b], acc[a][b], 0, 0, 0);
    }
  }

  // ---- epilogue ----
  float* o = out + (size_t)z * zstride;
  #pragma unroll
  for (int a = 0; a < 4; ++a) {
    int row = m0 + wid*64 + a*16 + lg*4;
    #pragma unroll
    for (int b = 0; b < 4; ++b) {
      int col = c0 + b*16 + lr;
      if (col < C) {
        float bv = bias ? bias[col] : 0.f;
        #pragma unroll
        for (int i = 0; i < 4; ++i)
          o[(size_t)(row+i)*ldo + col] = acc[a][b][i] + bv;
      }
    }
  }
}

// ---------------- K1c: reduce z-partials, leaky, emit bf16 X0H [512][320] ----------------
__global__ __launch_bounds__(256) void k1c_reduce(
    const float* __restrict__ part, int nz, unsigned short* __restrict__ X0Hbf)
{
  int idx = blockIdx.x*256 + threadIdx.x;
  if (idx >= B_*XLD) return;
  int m = idx / XLD, c = idx % XLD;
  float v = 0.f;
  if (c < D_) {
    for (int zz = 0; zz < nz; ++zz) v += part[(size_t)zz*B_*PLD + (size_t)m*PLD + c];
    v = (v >= 0.f) ? v : 0.1f*v;
  }
  X0Hbf[idx] = f2bf(v);
}

// ---------------- K3: per-row logsumexp -> lse[1024] ----------------
__global__ __launch_bounds__(256) void k3_lse(
    const float* __restrict__ out, float* __restrict__ lse)
{
  int row = blockIdx.x;
  const float* p; int C;
  if (row < B_) { p = out + (size_t)row*NG_; C = NG_; }
  else          { p = out + (size_t)B_*NG_ + (size_t)(row - B_)*NS_; C = NS_; }

  float m = -1e30f, s = 0.0f;
  for (int i = threadIdx.x; i < C; i += 256) {
    float v = p[i];
    float mn = fmaxf(m, v);
    s = s*__expf(m - mn) + __expf(v - mn);
    m = mn;
  }
  #pragma unroll
  for (int off = 32; off > 0; off >>= 1) {
    float m2 = __shfl_xor(m, off);
    float s2 = __shfl_xor(s, off);
    float mn = fmaxf(m, m2);
    s = s*__expf(m - mn) + s2*__expf(m2 - mn);
    m = mn;
  }
  __shared__ float ms[4], ss[4];
  int wid = threadIdx.x >> 6;
  if ((threadIdx.x & 63) == 0) { ms[wid] = m; ss[wid] = s; }
  __syncthreads();
  if (threadIdx.x == 0) {
    float M = ms[0], S = ss[0];
    #pragma unroll
    for (int w = 1; w < 4; ++w) {
      float mn = fmaxf(M, ms[w]);
      S = S*__expf(M - mn) + ss[w]*__expf(ms[w] - mn);
      M = mn;
    }
    lse[row] = M + __logf(S);
  }
}

// ---------------- K4: out -= lse[row], float4 ----------------
__global__ void k4_sub(float* __restrict__ out, const float* __restrict__ lse)
{
  const size_t g4 = (size_t)B_*NG_/4;
  const size_t total4 = g4 + (size_t)B_*NS_/4;
  size_t stride = (size_t)gridDim.x * blockDim.x;
  for (size_t i4 = (size_t)blockIdx.x*blockDim.x + threadIdx.x; i4 < total4; i4 += stride) {
    int row;
    if (i4 < g4) row = (int)(i4 / (NG_/4));
    else         row = B_ + (int)((i4 - g4) / (NS_/4));
    float l = lse[row];
    float4 v = reinterpret_cast<float4*>(out)[i4];
    v.x -= l; v.y -= l; v.z -= l; v.w -= l;
    reinterpret_cast<float4*>(out)[i4] = v;
  }
}

extern "C" void kernel_launch(void* const* d_in, const int* in_sizes, int n_in,
                              void* d_out, int out_size, void* d_ws, size_t ws_size,
                              hipStream_t stream)
{
  const float* x    = (const float*)d_in[0];
  const int*   ei   = (const int*)  d_in[1];
  const int*   et   = (const int*)  d_in[2];
  const float* Wrel = (const float*)d_in[3];
  const float* W0   = (const float*)d_in[4];
  const float* Wg   = (const float*)d_in[5];
  const float* bg   = (const float*)d_in[6];
  const float* Ws   = (const float*)d_in[7];
  const float* bs   = (const float*)d_in[8];
  float* out = (float*)d_out;

  // ws layout (floats): Y | X0Hbf | LSE | PART[z]
  float* wsf = (float*)d_ws;
  float* Y = wsf;
  size_t off = (size_t)B_*YLD;
  unsigned short* X0Hbf = (unsigned short*)(wsf + off);
  off += (size_t)B_*XLD/2;
  float* LSE = wsf + off;
  off += 1024;
  float* PART = wsf + off;
  size_t remain = (ws_size/4 > off) ? ws_size/4 - off : 0;
  int nz = 8;
  while (nz > 1 && (size_t)nz*B_*PLD > remain) nz >>= 1;

  k1a_coef_y<<<B_, 256, 0, stream>>>(x, ei, et, Y);

  // K1b: partials[z] = Y[512x2100] @ [Wrel;W0][2100x300]  (K-split over nz)
  gemm2<0><<<2*5*nz, 256, 0, stream>>>(
      Y, YLD, KTOT, 33, 6*D_, Wrel, W0, D_, D_,
      nullptr, PART, PLD, B_*PLD, 2, 5, nz, 0);

  // K1c: X0Hbf = bf16(leaky(sum_z partials))
  k1c_reduce<<<(B_*XLD + 255)/256, 256, 0, stream>>>(PART, nz, X0Hbf);

  // K2g: out[:, :NG] = X0Hbf @ Wg + bg
  gemm2<1><<<2*782, 256, 0, stream>>>(
      X0Hbf, XLD, D_, 5, D_, Wg, Wg, NG_, NG_, bg, out, NG_, 0, 2, 782, 1, 1);

  // K2s: out[:, NG:] = X0Hbf @ Ws + bs
  gemm2<1><<<2*391, 256, 0, stream>>>(
      X0Hbf, XLD, D_, 5, D_, Ws, Ws, NS_, NS_, bs, out + (size_t)B_*NG_, NS_, 0, 2, 391, 1, 1);

  k3_lse<<<2*B_, 256, 0, stream>>>(out, LSE);
  k4_sub<<<2048, 256, 0, stream>>>(out, LSE);
}